// Round 2
// baseline (517.370 us; speedup 1.0000x reference)
//
#include <hip/hip_runtime.h>
#include <hip/hip_bf16.h>
#include <cstdint>
#include <cstddef>

#define B_DIM 2
#define H_DIM 8
#define S_DIM 2048
#define D_DIM 512
#define BH_DIM 16
#define INV_TEMP 0.044194173824159216f
#define LN_EPS 1e-5f

typedef __attribute__((ext_vector_type(8))) __bf16 bf16x8;
typedef __attribute__((ext_vector_type(4))) __bf16 bf16x4;
typedef __attribute__((ext_vector_type(4))) float floatx4;

static __device__ __forceinline__ __bf16 to_bf16(float f) {
    unsigned u = __builtin_bit_cast(unsigned, f);
    u += 0x7fffu + ((u >> 16) & 1u);
    unsigned short h = (unsigned short)(u >> 16);
    return __builtin_bit_cast(__bf16, h);
}

static __device__ __forceinline__ floatx4 mfma_bf16(bf16x8 a, bf16x8 b, floatx4 c) {
    return __builtin_amdgcn_mfma_f32_16x16x32_bf16(a, b, c, 0, 0, 0);
}

// ---------------------------------------------------------------------------
// Kernel 1: QKV projections. out = x @ W^T + bias. 128x64 tile (768 blocks).
//   z=0: Q' = (q Wq^T + bq)/TEMP  -> Qs [BH][S][64] bf16
//   z=1: K' =  k Wk^T + bk        -> Ks [BH][S][64] bf16
//   z=2: V'^T (transposed)        -> Vt [BH][64][S] bf16
// ---------------------------------------------------------------------------
__global__ __launch_bounds__(256) void qkv_gemm(
    const float* __restrict__ q, const float* __restrict__ k, const float* __restrict__ v,
    const float* __restrict__ Wq, const float* __restrict__ bq,
    const float* __restrict__ Wk, const float* __restrict__ bk,
    const float* __restrict__ Wv, const float* __restrict__ bv,
    __bf16* __restrict__ Qs, __bf16* __restrict__ Ks, __bf16* __restrict__ Vt)
{
    const int z = blockIdx.z;
    const float* xin  = (z == 0) ? q  : (z == 1) ? k  : v;
    const float* W    = (z == 0) ? Wq : (z == 1) ? Wk : Wv;
    const float* bias = (z == 0) ? bq : (z == 1) ? bk : bv;

    __shared__ __bf16 As[128 * 72];
    __shared__ __bf16 Bs[64 * 72];

    const int tid = threadIdx.x;
    const int m0 = blockIdx.x * 128;
    const int n0 = blockIdx.y * 64;
    const int wave = tid >> 6, lane = tid & 63;
    const int lr = lane & 15, lq = lane >> 4;
    const int wm = wave * 32;

    floatx4 acc[2][4] = {};

    for (int k0 = 0; k0 < 512; k0 += 64) {
        for (int i = 0; i < 8; i++) {               // A: 128x64
            int idx = tid + i * 256;
            int row = idx >> 4, c4 = (idx & 15) * 4;
            float4 a = *(const float4*)(xin + (size_t)(m0 + row) * 512 + k0 + c4);
            __bf16* da = &As[row * 72 + c4];
            da[0] = to_bf16(a.x); da[1] = to_bf16(a.y); da[2] = to_bf16(a.z); da[3] = to_bf16(a.w);
        }
        for (int i = 0; i < 4; i++) {               // B: 64x64
            int idx = tid + i * 256;
            int row = idx >> 4, c4 = (idx & 15) * 4;
            float4 w4 = *(const float4*)(W + (size_t)(n0 + row) * 512 + k0 + c4);
            __bf16* db = &Bs[row * 72 + c4];
            db[0] = to_bf16(w4.x); db[1] = to_bf16(w4.y); db[2] = to_bf16(w4.z); db[3] = to_bf16(w4.w);
        }
        __syncthreads();
        for (int kk = 0; kk < 64; kk += 32) {
            bf16x8 af[2], bfr[4];
            for (int mi = 0; mi < 2; mi++)
                af[mi] = *(const bf16x8*)&As[(wm + mi * 16 + lr) * 72 + kk + lq * 8];
            for (int ni = 0; ni < 4; ni++)
                bfr[ni] = *(const bf16x8*)&Bs[(ni * 16 + lr) * 72 + kk + lq * 8];
            for (int mi = 0; mi < 2; mi++)
                for (int ni = 0; ni < 4; ni++)
                    acc[mi][ni] = mfma_bf16(af[mi], bfr[ni], acc[mi][ni]);
        }
        __syncthreads();
    }

    for (int ni = 0; ni < 4; ni++) {
        int gn = n0 + ni * 16 + lr;
        float bb = bias[gn];
        int h = gn >> 6, dd = gn & 63;
        for (int mi = 0; mi < 2; mi++) {
            for (int r = 0; r < 4; r++) {
                int gm = m0 + wm + mi * 16 + lq * 4 + r;
                int bat = gm >> 11, s = gm & 2047;
                int bh = bat * 8 + h;
                float val = acc[mi][ni][r] + bb;
                if (z == 0)      Qs[((size_t)bh * S_DIM + s) * 64 + dd] = to_bf16(val * INV_TEMP);
                else if (z == 1) Ks[((size_t)bh * S_DIM + s) * 64 + dd] = to_bf16(val);
                else             Vt[((size_t)bh * 64 + dd) * S_DIM + s] = to_bf16(val);
            }
        }
    }
}

// ---------------------------------------------------------------------------
// Kernel 2a: softmax denominators. One wave = 16 q rows over full K.
// Max-free (logits bounded ~4.5). Writes linv[bh][s] = 1/sum.
// ---------------------------------------------------------------------------
__global__ __launch_bounds__(256) void lsum_kernel(
    const __bf16* __restrict__ Qs, const __bf16* __restrict__ Ks,
    float* __restrict__ linv_arr)
{
    const int bh = blockIdx.y;
    const int wave = threadIdx.x >> 6, lane = threadIdx.x & 63;
    const int lr = lane & 15, lq = lane >> 4;
    const int qw = blockIdx.x * 64 + wave * 16;

    const __bf16* Qh = Qs + (size_t)bh * S_DIM * 64;
    const __bf16* Kh = Ks + (size_t)bh * S_DIM * 64;

    bf16x8 aq0 = *(const bf16x8*)(Qh + (size_t)(qw + lr) * 64 + lq * 8);
    bf16x8 aq1 = *(const bf16x8*)(Qh + (size_t)(qw + lr) * 64 + 32 + lq * 8);

    float lsum[4] = {0.f, 0.f, 0.f, 0.f};
    #pragma unroll 2
    for (int kt = 0; kt < S_DIM; kt += 64) {
        floatx4 s[4] = {};
        bf16x8 bfr[4][2];
        for (int t = 0; t < 4; t++) {
            bfr[t][0] = *(const bf16x8*)(Kh + (size_t)(kt + t * 16 + lr) * 64 + lq * 8);
            bfr[t][1] = *(const bf16x8*)(Kh + (size_t)(kt + t * 16 + lr) * 64 + 32 + lq * 8);
        }
        for (int t = 0; t < 4; t++) {
            s[t] = mfma_bf16(aq0, bfr[t][0], s[t]);
            s[t] = mfma_bf16(aq1, bfr[t][1], s[t]);
        }
        for (int t = 0; t < 4; t++)
            for (int r = 0; r < 4; r++) lsum[r] += __expf(s[t][r]);
    }
    for (int m = 1; m < 16; m <<= 1)
        for (int r = 0; r < 4; r++) lsum[r] += __shfl_xor(lsum[r], m);
    if (lr == 0)
        for (int r = 0; r < 4; r++)
            linv_arr[(size_t)bh * S_DIM + qw + lq * 4 + r] = 1.0f / lsum[r];
}

// ---------------------------------------------------------------------------
// Kernel 2b: attention + PV, K-split x4 (grid 32x16x4 = 8192 waves, 100% occ).
// Each block: 64 q rows (4 waves x 16), one 512-col K-quarter. Writes its
// slice of attn (write-once) and a fp32 O-partial. No __syncthreads: the
// P transpose LDS tile is per-wave; wave_barrier() only fences the compiler
// (DS ops complete in order per wave).
// ---------------------------------------------------------------------------
__global__ __launch_bounds__(256) void attn_pv(
    const __bf16* __restrict__ Qs, const __bf16* __restrict__ Ks, const __bf16* __restrict__ Vt,
    const float* __restrict__ linv_arr,
    float* __restrict__ attn_out, float* __restrict__ Opart)
{
    const int bh = blockIdx.y;
    const int b = bh >> 3, h = bh & 7;
    const int kq = blockIdx.z;
    const int wave = threadIdx.x >> 6, lane = threadIdx.x & 63;
    const int lr = lane & 15, lq = lane >> 4;
    const int qw = blockIdx.x * 64 + wave * 16;

    const __bf16* Qh = Qs + (size_t)bh * S_DIM * 64;
    const __bf16* Kh = Ks + (size_t)bh * S_DIM * 64;
    const __bf16* Vh = Vt + (size_t)bh * 64 * S_DIM;

    bf16x8 aq0 = *(const bf16x8*)(Qh + (size_t)(qw + lr) * 64 + lq * 8);
    bf16x8 aq1 = *(const bf16x8*)(Qh + (size_t)(qw + lr) * 64 + 32 + lq * 8);

    float linvr[4];
    for (int r = 0; r < 4; r++)
        linvr[r] = linv_arr[(size_t)bh * S_DIM + qw + lq * 4 + r];

    __shared__ __bf16 Pst[4][16][40];
    floatx4 o[4] = {};
    float* aout = attn_out + ((size_t)(h * B_DIM + b) * S_DIM + qw) * S_DIM;
    const int kbeg = kq * 512;

    #pragma unroll 4
    for (int kt = kbeg; kt < kbeg + 512; kt += 32) {
        floatx4 s0 = {}, s1 = {};
        bf16x8 b00 = *(const bf16x8*)(Kh + (size_t)(kt + lr) * 64 + lq * 8);
        bf16x8 b01 = *(const bf16x8*)(Kh + (size_t)(kt + lr) * 64 + 32 + lq * 8);
        bf16x8 b10 = *(const bf16x8*)(Kh + (size_t)(kt + 16 + lr) * 64 + lq * 8);
        bf16x8 b11 = *(const bf16x8*)(Kh + (size_t)(kt + 16 + lr) * 64 + 32 + lq * 8);
        s0 = mfma_bf16(aq0, b00, s0); s0 = mfma_bf16(aq1, b01, s0);
        s1 = mfma_bf16(aq0, b10, s1); s1 = mfma_bf16(aq1, b11, s1);

        float p0[4], p1[4];
        for (int r = 0; r < 4; r++) {
            p0[r] = __expf(s0[r]) * linvr[r];
            p1[r] = __expf(s1[r]) * linvr[r];
        }
        for (int r = 0; r < 4; r++) {
            aout[(size_t)(lq * 4 + r) * S_DIM + kt + lr]      = p0[r];
            aout[(size_t)(lq * 4 + r) * S_DIM + kt + 16 + lr] = p1[r];
        }
        for (int r = 0; r < 4; r++) {
            Pst[wave][lq * 4 + r][lr]      = to_bf16(p0[r]);
            Pst[wave][lq * 4 + r][lr + 16] = to_bf16(p1[r]);
        }
        __builtin_amdgcn_wave_barrier();
        bf16x8 pa = *(const bf16x8*)&Pst[wave][lr][lq * 8];
        __builtin_amdgcn_wave_barrier();
        for (int ni = 0; ni < 4; ni++) {
            bf16x8 vb = *(const bf16x8*)(Vh + (size_t)(ni * 16 + lr) * S_DIM + kt + lq * 8);
            o[ni] = mfma_bf16(pa, vb, o[ni]);
        }
    }

    // O partial: [kq][b][s][512] fp32
    float* op = Opart + (((size_t)(kq * B_DIM + b) * S_DIM + qw) * 512) + h * 64;
    for (int ni = 0; ni < 4; ni++)
        for (int r = 0; r < 4; r++)
            op[(size_t)(lq * 4 + r) * 512 + ni * 16 + lr] = o[ni][r];
}

// ---------------------------------------------------------------------------
// Kernel 2c: sum the 4 O-partials -> ctx bf16 [b][s][512].
// ---------------------------------------------------------------------------
__global__ __launch_bounds__(256) void reduce_o(
    const float* __restrict__ Opart, __bf16* __restrict__ ctx)
{
    const size_t i = (size_t)blockIdx.x * 256 + threadIdx.x;   // one float4 per thread
    const size_t STRIDE4 = (size_t)B_DIM * S_DIM * 512 / 4;    // 524288
    const float4* p = (const float4*)Opart;
    float4 a = p[i];
    float4 b2 = p[i + STRIDE4];
    float4 c = p[i + 2 * STRIDE4];
    float4 d = p[i + 3 * STRIDE4];
    float x0 = a.x + b2.x + c.x + d.x;
    float x1 = a.y + b2.y + c.y + d.y;
    float x2 = a.z + b2.z + c.z + d.z;
    float x3 = a.w + b2.w + c.w + d.w;
    bf16x4 o; o[0] = to_bf16(x0); o[1] = to_bf16(x1); o[2] = to_bf16(x2); o[3] = to_bf16(x3);
    *(bf16x4*)(ctx + i * 4) = o;
}

// ---------------------------------------------------------------------------
// Kernel 3: fc projection, 64x64 tiles (512 blocks). fco = ctx @ Wfc^T + bfc.
// ---------------------------------------------------------------------------
__global__ __launch_bounds__(256) void fc_gemm(
    const __bf16* __restrict__ ctx, const float* __restrict__ Wfc,
    const float* __restrict__ bfc, float* __restrict__ fc_out)
{
    __shared__ __bf16 As[64 * 72];
    __shared__ __bf16 Bs[64 * 72];
    const int tid = threadIdx.x;
    const int m0 = blockIdx.x * 64, n0 = blockIdx.y * 64;
    const int wave = tid >> 6, lane = tid & 63;
    const int lr = lane & 15, lq = lane >> 4;
    const int wm = (wave & 1) * 32, wn = (wave >> 1) * 32;
    floatx4 acc[2][2] = {};

    for (int k0 = 0; k0 < 512; k0 += 64) {
        for (int i = 0; i < 2; i++) {               // A: 64x64 bf16 copy
            int idx = tid + i * 256;
            int row = idx >> 3, c8 = (idx & 7) * 8;
            *(bf16x8*)&As[row * 72 + c8] =
                *(const bf16x8*)(ctx + (size_t)(m0 + row) * 512 + k0 + c8);
        }
        for (int i = 0; i < 4; i++) {               // B: 64x64 fp32 -> bf16
            int idx = tid + i * 256;
            int row = idx >> 4, c4 = (idx & 15) * 4;
            float4 w4 = *(const float4*)(Wfc + (size_t)(n0 + row) * 512 + k0 + c4);
            __bf16* db = &Bs[row * 72 + c4];
            db[0] = to_bf16(w4.x); db[1] = to_bf16(w4.y); db[2] = to_bf16(w4.z); db[3] = to_bf16(w4.w);
        }
        __syncthreads();
        for (int kk = 0; kk < 64; kk += 32) {
            bf16x8 af[2], bfr[2];
            for (int mi = 0; mi < 2; mi++)
                af[mi] = *(const bf16x8*)&As[(wm + mi * 16 + lr) * 72 + kk + lq * 8];
            for (int ni = 0; ni < 2; ni++)
                bfr[ni] = *(const bf16x8*)&Bs[(wn + ni * 16 + lr) * 72 + kk + lq * 8];
            for (int mi = 0; mi < 2; mi++)
                for (int ni = 0; ni < 2; ni++)
                    acc[mi][ni] = mfma_bf16(af[mi], bfr[ni], acc[mi][ni]);
        }
        __syncthreads();
    }

    for (int ni = 0; ni < 2; ni++) {
        int gn = n0 + wn + ni * 16 + lr;
        float bb = bfc[gn];
        for (int mi = 0; mi < 2; mi++)
            for (int r = 0; r < 4; r++) {
                int gm = m0 + wm + mi * 16 + lq * 4 + r;
                fc_out[(size_t)gm * 512 + gn] = acc[mi][ni][r] + bb;
            }
    }
}

// ---------------------------------------------------------------------------
// Kernel 4: residual add + LayerNorm. One block per row (512 cols).
// ---------------------------------------------------------------------------
__global__ __launch_bounds__(256) void ln_kernel(
    const float* __restrict__ fc_out, const float* __restrict__ qres,
    const float* __restrict__ gamma, const float* __restrict__ beta,
    float* __restrict__ y)
{
    const int row = blockIdx.x;
    const int tid = threadIdx.x;
    const size_t base = (size_t)row * 512;
    float x0 = fc_out[base + tid] + qres[base + tid];
    float x1 = fc_out[base + 256 + tid] + qres[base + 256 + tid];
    float s = x0 + x1, s2 = x0 * x0 + x1 * x1;
    for (int m = 1; m < 64; m <<= 1) { s += __shfl_xor(s, m); s2 += __shfl_xor(s2, m); }
    __shared__ float sw[4], sw2[4];
    const int wave = tid >> 6, lane = tid & 63;
    if (lane == 0) { sw[wave] = s; sw2[wave] = s2; }
    __syncthreads();
    s  = sw[0] + sw[1] + sw[2] + sw[3];
    s2 = sw2[0] + sw2[1] + sw2[2] + sw2[3];
    const float mu  = s * (1.0f / 512.0f);
    const float var = s2 * (1.0f / 512.0f) - mu * mu;
    const float rs  = rsqrtf(var + LN_EPS);
    y[base + tid]       = (x0 - mu) * rs * gamma[tid] + beta[tid];
    y[base + 256 + tid] = (x1 - mu) * rs * gamma[tid + 256] + beta[tid + 256];
}

// ---------------------------------------------------------------------------
extern "C" void kernel_launch(void* const* d_in, const int* in_sizes, int n_in,
                              void* d_out, int out_size, void* d_ws, size_t ws_size,
                              hipStream_t stream) {
    const float* q    = (const float*)d_in[0];
    const float* k    = (const float*)d_in[1];
    const float* v    = (const float*)d_in[2];
    const float* Wq   = (const float*)d_in[3];
    const float* bq   = (const float*)d_in[4];
    const float* Wk   = (const float*)d_in[5];
    const float* bk   = (const float*)d_in[6];
    const float* Wv   = (const float*)d_in[7];
    const float* bv   = (const float*)d_in[8];
    const float* Wfc  = (const float*)d_in[9];
    const float* bfc  = (const float*)d_in[10];
    const float* gam  = (const float*)d_in[11];
    const float* bet  = (const float*)d_in[12];

    float* y    = (float*)d_out;
    float* attn = y + (size_t)B_DIM * S_DIM * D_DIM;

    char* ws = (char*)d_ws;
    __bf16* Qs    = (__bf16*)(ws);                        // [0,4MB)   [BH][S][64]
    __bf16* Ks    = (__bf16*)(ws + ((size_t)4 << 20));    // [4,8MB)   [BH][S][64]
    __bf16* Vt    = (__bf16*)(ws + ((size_t)8 << 20));    // [8,12MB)  [BH][64][S]
    float*  Opart = (float*)(ws + ((size_t)12 << 20));    // [12,44MB) [4][B][S][512] fp32
    float*  linv  = (float*)(ws + ((size_t)44 << 20));    // [44,44.125MB)
    // aliases (safe: writers run after last readers of the aliased regions)
    __bf16* ctx = (__bf16*)(ws);                          // over Qs  (after attn_pv)
    float*  fco = (float*)(ws + ((size_t)4 << 20));       // over Ks+Vt (after attn_pv)

    qkv_gemm<<<dim3(32, 8, 3), 256, 0, stream>>>(q, k, v, Wq, bq, Wk, bk, Wv, bv, Qs, Ks, Vt);
    lsum_kernel<<<dim3(32, 16), 256, 0, stream>>>(Qs, Ks, linv);
    attn_pv<<<dim3(32, 16, 4), 256, 0, stream>>>(Qs, Ks, Vt, linv, attn, Opart);
    reduce_o<<<dim3(2048), 256, 0, stream>>>(Opart, ctx);
    fc_gemm<<<dim3(64, 8), 256, 0, stream>>>(ctx, Wfc, bfc, fco);
    ln_kernel<<<dim3(4096), 256, 0, stream>>>(fco, q, gam, bet, y);
}